// Round 1
// baseline (2360.073 us; speedup 1.0000x reference)
//
#include <hip/hip_runtime.h>
#include <cstddef>

#define T_STEPS 24
#define F_IN 64
#define H_DIM 128
#define ROWS_PER_BLOCK 64
#define NUM_BLOCKS 325   // 20800 / 64

typedef _Float16 f16;
typedef _Float16 half8 __attribute__((ext_vector_type(8)));
typedef float floatx16 __attribute__((ext_vector_type(16)));
typedef float floatx4 __attribute__((ext_vector_type(4)));

__device__ __forceinline__ floatx16 zero16() {
    floatx16 z = {0.f,0.f,0.f,0.f,0.f,0.f,0.f,0.f,0.f,0.f,0.f,0.f,0.f,0.f,0.f,0.f};
    return z;
}

#define MFMA32(acc, a, b) (acc) = __builtin_amdgcn_mfma_f32_32x32x16_f16((a), (b), (acc), 0, 0, 0)

__device__ __forceinline__ float sigm(float v) {
    v = fminf(fmaxf(v, -30.f), 30.f);
    return 1.f / (1.f + __expf(-v));
}
__device__ __forceinline__ float tanhf_(float v) {
    v = fminf(fmaxf(v, -15.f), 15.f);
    float e = __expf(-2.f * v);
    return (1.f - e) / (1.f + e);
}

__global__ void cvt_f32_f16(const float* __restrict__ src, f16* __restrict__ dst, int n) {
    int i = blockIdx.x * 256 + threadIdx.x;
    if (i < n) dst[i] = (f16)src[i];
}

__global__ __launch_bounds__(256, 2) void gru_fused(
    const float* __restrict__ x,
    const float* __restrict__ b_ih, const float* __restrict__ b_hh,
    const float* __restrict__ gate_b, const float* __restrict__ out_b,
    const f16* __restrict__ wih, const f16* __restrict__ whh,
    const f16* __restrict__ gw, const f16* __restrict__ ow,
    float* __restrict__ out)
{
    // row strides are odd multiples of 16B -> conflict-free-baseline ds_read_b128
    __shared__ f16 sX[64][72];
    __shared__ f16 sH0[64][136];
    __shared__ f16 sH1[64][136];
    __shared__ f16 sRH[64][136];

    const int tid  = threadIdx.x;
    const int lane = tid & 63;
    const int wave = tid >> 6;
    const int wr   = wave >> 1;   // row-tile (32 rows)
    const int wc   = wave & 1;    // column half
    const int m    = lane & 31;
    const int kh   = lane >> 5;
    const int row0 = blockIdx.x * ROWS_PER_BLOCK;
    const int arow = 32 * wr + m;

    for (int i = tid; i < 64 * 136; i += 256) {
        (&sH0[0][0])[i] = (f16)0.f;
        (&sH1[0][0])[i] = (f16)0.f;
    }

    float bR[2], bZ[2], bIN[2], bHN[2], bGR[2], bGZ[2], bO[2];
    #pragma unroll
    for (int jj = 0; jj < 2; ++jj) {
        const int c = 64 * wc + 32 * jj + m;
        bR[jj]  = b_ih[c]       + b_hh[c];
        bZ[jj]  = b_ih[128 + c] + b_hh[128 + c];
        bIN[jj] = b_ih[256 + c];
        bHN[jj] = b_hh[256 + c];
        bGR[jj] = gate_b[c];
        bGZ[jj] = gate_b[128 + c];
        bO[jj]  = out_b[c];
    }

    // persistent recurrent state, fp32, in MFMA C-layout
    floatx16 h0p[2], h1p[2];
    h0p[0] = zero16(); h0p[1] = zero16();
    h1p[0] = zero16(); h1p[1] = zero16();

    __syncthreads();

    for (int t = 0; t < T_STEPS; ++t) {
        // ---- stage x_t -> sX (fp32 -> fp16) ----
        {
            const int rr = tid >> 2;
            const int f0 = (tid & 3) * 16;
            const floatx4* xv = (const floatx4*)(x + ((size_t)(row0 + rr) * T_STEPS + t) * F_IN + f0);
            floatx4 v0 = xv[0], v1 = xv[1], v2 = xv[2], v3 = xv[3];
            half8 p0, p1;
            p0[0]=(f16)v0[0]; p0[1]=(f16)v0[1]; p0[2]=(f16)v0[2]; p0[3]=(f16)v0[3];
            p0[4]=(f16)v1[0]; p0[5]=(f16)v1[1]; p0[6]=(f16)v1[2]; p0[7]=(f16)v1[3];
            p1[0]=(f16)v2[0]; p1[1]=(f16)v2[1]; p1[2]=(f16)v2[2]; p1[3]=(f16)v2[3];
            p1[4]=(f16)v3[0]; p1[5]=(f16)v3[1]; p1[6]=(f16)v3[2]; p1[7]=(f16)v3[3];
            *(half8*)&sX[rr][f0]     = p0;
            *(half8*)&sX[rr][f0 + 8] = p1;
        }
        __syncthreads();   // S1: sX ready

        // ---- layer 0: torch GRUCell ----
        half8 ax[4], ah[8];
        #pragma unroll
        for (int kc = 0; kc < 4; ++kc) ax[kc] = *(const half8*)&sX[arow][kc * 16 + kh * 8];
        #pragma unroll
        for (int kc = 0; kc < 8; ++kc) ah[kc] = *(const half8*)&sH0[arow][kc * 16 + kh * 8];
        __syncthreads();   // S2: every wave has captured old h0

        #pragma unroll
        for (int jj = 0; jj < 2; ++jj) {
            const int orr = (2 * wc + jj) * 32 + m;
            const f16* wih_r = wih + (size_t)orr * 64;
            const f16* wih_z = wih + (size_t)(128 + orr) * 64;
            const f16* wih_n = wih + (size_t)(256 + orr) * 64;
            const f16* whh_r = whh + (size_t)orr * 128;
            const f16* whh_z = whh + (size_t)(128 + orr) * 128;
            const f16* whh_n = whh + (size_t)(256 + orr) * 128;
            floatx16 aR = zero16(), aZ = zero16(), aIN = zero16(), aHN = zero16();
            #pragma unroll
            for (int kc = 0; kc < 4; ++kc) {
                const int ko = kc * 16 + kh * 8;
                MFMA32(aR,  ax[kc], *(const half8*)(wih_r + ko));
                MFMA32(aZ,  ax[kc], *(const half8*)(wih_z + ko));
                MFMA32(aIN, ax[kc], *(const half8*)(wih_n + ko));
            }
            #pragma unroll
            for (int kc = 0; kc < 8; ++kc) {
                const int ko = kc * 16 + kh * 8;
                MFMA32(aR,  ah[kc], *(const half8*)(whh_r + ko));
                MFMA32(aZ,  ah[kc], *(const half8*)(whh_z + ko));
                MFMA32(aHN, ah[kc], *(const half8*)(whh_n + ko));
            }
            #pragma unroll
            for (int i = 0; i < 16; ++i) {
                float r = sigm(aR[i] + bR[jj]);
                float z = sigm(aZ[i] + bZ[jj]);
                float n = tanhf_(aIN[i] + bIN[jj] + r * (aHN[i] + bHN[jj]));
                h0p[jj][i] = (1.f - z) * n + z * h0p[jj][i];
            }
        }
        // publish new h0 (fp16) for layer-1 input and next step's recurrence
        #pragma unroll
        for (int jj = 0; jj < 2; ++jj) {
            const int colb = 64 * wc + 32 * jj + m;
            #pragma unroll
            for (int i = 0; i < 16; ++i) {
                const int rowi = (i & 3) + 8 * (i >> 2) + 4 * kh;
                sH0[32 * wr + rowi][colb] = (f16)h0p[jj][i];
            }
        }
        __syncthreads();   // S3: new h0 visible

        // ---- layer 1: gate GEMM  (xh = [h0_new | h1]) ----
        half8 axh[16];
        #pragma unroll
        for (int kc = 0; kc < 8; ++kc) axh[kc]     = *(const half8*)&sH0[arow][kc * 16 + kh * 8];
        #pragma unroll
        for (int kc = 0; kc < 8; ++kc) axh[8 + kc] = *(const half8*)&sH1[arow][kc * 16 + kh * 8];

        floatx16 gRa[2], gZa[2];
        #pragma unroll
        for (int jj = 0; jj < 2; ++jj) {
            const int orr = (2 * wc + jj) * 32 + m;
            const f16* gw_r = gw + (size_t)orr * 256;
            const f16* gw_z = gw + (size_t)(128 + orr) * 256;
            gRa[jj] = zero16(); gZa[jj] = zero16();
            #pragma unroll
            for (int kc = 0; kc < 16; ++kc) {
                const int ko = kc * 16 + kh * 8;
                MFMA32(gRa[jj], axh[kc], *(const half8*)(gw_r + ko));
                MFMA32(gZa[jj], axh[kc], *(const half8*)(gw_z + ko));
            }
        }
        float zk[2][16];
        #pragma unroll
        for (int jj = 0; jj < 2; ++jj) {
            const int colb = 64 * wc + 32 * jj + m;
            #pragma unroll
            for (int i = 0; i < 16; ++i) {
                const int rowi = (i & 3) + 8 * (i >> 2) + 4 * kh;
                float r = sigm(gRa[jj][i] + bGR[jj]);
                zk[jj][i] = sigm(gZa[jj][i] + bGZ[jj]);
                sRH[32 * wr + rowi][colb] = (f16)(r * h1p[jj][i]);
            }
        }
        __syncthreads();   // S4: sRH ready; old h1 fully consumed

        // ---- layer 1: candidate GEMM (xrh = [h0_new | r*h1]) + output ----
        half8 arh[8];
        #pragma unroll
        for (int kc = 0; kc < 8; ++kc) arh[kc] = *(const half8*)&sRH[arow][kc * 16 + kh * 8];
        #pragma unroll
        for (int jj = 0; jj < 2; ++jj) {
            const int orr = (2 * wc + jj) * 32 + m;
            const f16* ow_x = ow + (size_t)orr * 256;
            floatx16 aC = zero16();
            #pragma unroll
            for (int kc = 0; kc < 8; ++kc) {
                const int ko = kc * 16 + kh * 8;
                MFMA32(aC, axh[kc], *(const half8*)(ow_x + ko));
                MFMA32(aC, arh[kc], *(const half8*)(ow_x + 128 + ko));
            }
            const int colb = 64 * wc + 32 * jj + m;
            #pragma unroll
            for (int i = 0; i < 16; ++i) {
                const int rowi = (i & 3) + 8 * (i >> 2) + 4 * kh;
                float cd = tanhf_(aC[i] + bO[jj]);
                float z  = zk[jj][i];
                float hv = z * h1p[jj][i] + (1.f - z) * cd;
                h1p[jj][i] = hv;
                sH1[32 * wr + rowi][colb] = (f16)hv;
                out[((size_t)(row0 + 32 * wr + rowi) * T_STEPS + t) * H_DIM + colb] = hv;
            }
        }
        // no barrier needed here: next iteration's S1..S3 order all hazards
    }
}

extern "C" void kernel_launch(void* const* d_in, const int* in_sizes, int n_in,
                              void* d_out, int out_size, void* d_ws, size_t ws_size,
                              hipStream_t stream) {
    (void)in_sizes; (void)n_in; (void)out_size; (void)ws_size;
    const float* x      = (const float*)d_in[0];
    const float* w_ih   = (const float*)d_in[1];
    const float* w_hh   = (const float*)d_in[2];
    const float* b_ih   = (const float*)d_in[3];
    const float* b_hh   = (const float*)d_in[4];
    const float* gate_w = (const float*)d_in[5];
    const float* gate_b = (const float*)d_in[6];
    const float* out_w  = (const float*)d_in[7];
    const float* out_b  = (const float*)d_in[8];

    f16* wsH = (f16*)d_ws;
    f16* wih = wsH;                 // 384*64   = 24576 halves
    f16* whh = wsH + 24576;         // 384*128  = 49152
    f16* gw  = wsH + 73728;         // 256*256  = 65536
    f16* ow  = wsH + 139264;        // 128*256  = 32768  (end 172032 halves = 344 KB)

    cvt_f32_f16<<<(24576 + 255) / 256, 256, 0, stream>>>(w_ih, wih, 24576);
    cvt_f32_f16<<<(49152 + 255) / 256, 256, 0, stream>>>(w_hh, whh, 49152);
    cvt_f32_f16<<<(65536 + 255) / 256, 256, 0, stream>>>(gate_w, gw, 65536);
    cvt_f32_f16<<<(32768 + 255) / 256, 256, 0, stream>>>(out_w, ow, 32768);

    gru_fused<<<NUM_BLOCKS, 256, 0, stream>>>(x, b_ih, b_hh, gate_b, out_b,
                                              wih, whh, gw, ow, (float*)d_out);
}

// Round 2
// 777.796 us; speedup vs baseline: 3.0343x; 3.0343x over previous
//
#include <hip/hip_runtime.h>
#include <cstddef>

#define T_STEPS 24
#define F_IN 64
#define H_DIM 128
#define ROWS 32
#define NUM_BLOCKS 650   // 20800 / 32

typedef _Float16 f16;
typedef _Float16 half8 __attribute__((ext_vector_type(8)));
typedef _Float16 half4 __attribute__((ext_vector_type(4)));
typedef float floatx4 __attribute__((ext_vector_type(4)));

#define MFMA16(acc, a, b) (acc) = __builtin_amdgcn_mfma_f32_16x16x32_f16((a), (b), (acc), 0, 0, 0)

__device__ __forceinline__ float sigm(float v) {
    v = fminf(fmaxf(v, -30.f), 30.f);
    return 1.f / (1.f + __expf(-v));
}
__device__ __forceinline__ float tanhf_(float v) {
    v = fminf(fmaxf(v, -15.f), 15.f);
    float e = __expf(-2.f * v);
    return (1.f - e) / (1.f + e);
}

__global__ void cvt_f32_f16(const float* __restrict__ src, f16* __restrict__ dst, int n) {
    int i = blockIdx.x * 256 + threadIdx.x;
    if (i < n) dst[i] = (f16)src[i];
}

// 8 waves/block: wave w owns output columns [16w, 16w+16); 32 rows/block (2 row-tiles
// of 16 per wave). ALL weight B-fragments live in registers (168 VGPR/lane), loaded
// once; only activations go through LDS. __launch_bounds__(512,2) -> VGPR cap 256.
__global__ __launch_bounds__(512, 2) void gru_fused(
    const float* __restrict__ x,
    const float* __restrict__ b_ih, const float* __restrict__ b_hh,
    const float* __restrict__ gate_b, const float* __restrict__ out_b,
    const f16* __restrict__ wih, const f16* __restrict__ whh,
    const f16* __restrict__ gw, const f16* __restrict__ ow,
    float* __restrict__ out)
{
    __shared__ f16 sX[32][72];       // x_t tile, fp16
    __shared__ f16 sH0a[32][136];    // h0 double buffer
    __shared__ f16 sH0b[32][136];
    __shared__ f16 sH1[32][136];     // h1 (single buffer; hazards ordered by B2/B3)
    __shared__ f16 sRH[32][136];     // r * h1

    const int tid  = threadIdx.x;
    const int lane = tid & 63;
    const int wv   = tid >> 6;      // 0..7 -> column tile
    const int p    = lane & 15;     // col-in-tile (B frag) / row-in-tile (A frag)
    const int quad = lane >> 4;     // 0..3
    const int ko   = quad * 8;      // k-offset within a K=32 chunk
    const int c    = wv * 16 + p;   // global output column 0..127
    const int row0 = blockIdx.x * ROWS;

    // zero-init h state buffers read at t=0
    for (int i = tid; i < (32 * 136) / 2; i += 512) {
        ((unsigned int*)&sH0a[0][0])[i] = 0u;
        ((unsigned int*)&sH1[0][0])[i]  = 0u;
    }

    // per-column biases
    const float bR  = b_ih[c] + b_hh[c];
    const float bZ  = b_ih[128 + c] + b_hh[128 + c];
    const float bIN = b_ih[256 + c];
    const float bHN = b_hh[256 + c];
    const float bGR = gate_b[c];
    const float bGZ = gate_b[128 + c];
    const float bO  = out_b[c];

    // ---- weight-stationary B fragments (n = c, k = kc*32 + quad*8 + j) ----
    half8 Wih[3][2], Whh[3][4], Wgw[2][8], Wow[8];
    #pragma unroll
    for (int g = 0; g < 3; ++g) {
        #pragma unroll
        for (int kc = 0; kc < 2; ++kc)
            Wih[g][kc] = *(const half8*)(wih + (size_t)(g * 128 + c) * 64 + kc * 32 + ko);
        #pragma unroll
        for (int kc = 0; kc < 4; ++kc)
            Whh[g][kc] = *(const half8*)(whh + (size_t)(g * 128 + c) * 128 + kc * 32 + ko);
    }
    #pragma unroll
    for (int g = 0; g < 2; ++g)
        #pragma unroll
        for (int kc = 0; kc < 8; ++kc)
            Wgw[g][kc] = *(const half8*)(gw + (size_t)(g * 128 + c) * 256 + kc * 32 + ko);
    #pragma unroll
    for (int kc = 0; kc < 8; ++kc)
        Wow[kc] = *(const half8*)(ow + (size_t)c * 256 + kc * 32 + ko);

    // recurrent state, fp32, C-layout: element i -> row rt*16 + quad*4 + i, col c
    floatx4 h0p[2], h1p[2];
    h0p[0] = (floatx4){0.f,0.f,0.f,0.f}; h0p[1] = (floatx4){0.f,0.f,0.f,0.f};
    h1p[0] = (floatx4){0.f,0.f,0.f,0.f}; h1p[1] = (floatx4){0.f,0.f,0.f,0.f};

    __syncthreads();

    for (int t = 0; t < T_STEPS; ++t) {
        // ---- Seg1: stage x_t -> sX ----
        {
            const int rr = tid >> 4;
            const int f4 = (tid & 15) * 4;
            const floatx4 v = *(const floatx4*)(x + ((size_t)(row0 + rr) * T_STEPS + t) * F_IN + f4);
            half4 h; h[0] = (f16)v[0]; h[1] = (f16)v[1]; h[2] = (f16)v[2]; h[3] = (f16)v[3];
            *(half4*)&sX[rr][f4] = h;
        }
        __syncthreads();   // B1: sX visible

        const f16 (*sH0r)[136] = (t & 1) ? sH0b : sH0a;  // old h0
        f16 (*sH0w)[136]       = (t & 1) ? sH0a : sH0b;  // new h0

        // ---- Seg2: layer-0 GRUCell + gate-GEMM h1-partial ----
        floatx4 gR[2], gZ[2];
        #pragma unroll
        for (int rt = 0; rt < 2; ++rt) {
            floatx4 aR = (floatx4){0.f,0.f,0.f,0.f};
            floatx4 aZ = aR, aIN = aR, aHN = aR;
            #pragma unroll
            for (int kc = 0; kc < 2; ++kc) {
                const half8 ax = *(const half8*)&sX[rt * 16 + p][kc * 32 + ko];
                MFMA16(aR,  ax, Wih[0][kc]);
                MFMA16(aZ,  ax, Wih[1][kc]);
                MFMA16(aIN, ax, Wih[2][kc]);
            }
            #pragma unroll
            for (int kc = 0; kc < 4; ++kc) {
                const half8 ah = *(const half8*)&sH0r[rt * 16 + p][kc * 32 + ko];
                MFMA16(aR,  ah, Whh[0][kc]);
                MFMA16(aZ,  ah, Whh[1][kc]);
                MFMA16(aHN, ah, Whh[2][kc]);
            }
            // gate GEMM, h1 (old) part: xh k 128..255
            gR[rt] = (floatx4){0.f,0.f,0.f,0.f};
            gZ[rt] = (floatx4){0.f,0.f,0.f,0.f};
            #pragma unroll
            for (int kc = 0; kc < 4; ++kc) {
                const half8 a1 = *(const half8*)&sH1[rt * 16 + p][kc * 32 + ko];
                MFMA16(gR[rt], a1, Wgw[0][4 + kc]);
                MFMA16(gZ[rt], a1, Wgw[1][4 + kc]);
            }
            // layer-0 epilogue -> h0new (regs + fp16 publish into write buffer)
            #pragma unroll
            for (int i = 0; i < 4; ++i) {
                const float r = sigm(aR[i] + bR);
                const float z = sigm(aZ[i] + bZ);
                const float n = tanhf_(aIN[i] + bIN + r * (aHN[i] + bHN));
                const float h0 = (1.f - z) * n + z * h0p[rt][i];
                h0p[rt][i] = h0;
                sH0w[rt * 16 + quad * 4 + i][c] = (f16)h0;
            }
        }
        __syncthreads();   // B2: h0new visible

        // ---- Seg3: finish gate GEMM (h0new part), write r*h1 ----
        half8 a0[2][4];
        #pragma unroll
        for (int rt = 0; rt < 2; ++rt)
            #pragma unroll
            for (int kc = 0; kc < 4; ++kc)
                a0[rt][kc] = *(const half8*)&sH0w[rt * 16 + p][kc * 32 + ko];
        #pragma unroll
        for (int rt = 0; rt < 2; ++rt)
            #pragma unroll
            for (int kc = 0; kc < 4; ++kc) {
                MFMA16(gR[rt], a0[rt][kc], Wgw[0][kc]);
                MFMA16(gZ[rt], a0[rt][kc], Wgw[1][kc]);
            }
        floatx4 z1[2];
        #pragma unroll
        for (int rt = 0; rt < 2; ++rt)
            #pragma unroll
            for (int i = 0; i < 4; ++i) {
                const float r1 = sigm(gR[rt][i] + bGR);
                z1[rt][i] = sigm(gZ[rt][i] + bGZ);
                sRH[rt * 16 + quad * 4 + i][c] = (f16)(r1 * h1p[rt][i]);
            }
        __syncthreads();   // B3: sRH visible

        // ---- Seg4: candidate GEMM + h1 update + output ----
        #pragma unroll
        for (int rt = 0; rt < 2; ++rt) {
            floatx4 aC = (floatx4){0.f,0.f,0.f,0.f};
            #pragma unroll
            for (int kc = 0; kc < 4; ++kc)
                MFMA16(aC, a0[rt][kc], Wow[kc]);
            #pragma unroll
            for (int kc = 0; kc < 4; ++kc) {
                const half8 ar = *(const half8*)&sRH[rt * 16 + p][kc * 32 + ko];
                MFMA16(aC, ar, Wow[4 + kc]);
            }
            #pragma unroll
            for (int i = 0; i < 4; ++i) {
                const float cd = tanhf_(aC[i] + bO);
                const float zz = z1[rt][i];
                const float hv = zz * h1p[rt][i] + (1.f - zz) * cd;
                h1p[rt][i] = hv;
                sH1[rt * 16 + quad * 4 + i][c] = (f16)hv;
                out[((size_t)(row0 + rt * 16 + quad * 4 + i) * T_STEPS + t) * H_DIM + c] = hv;
            }
        }
        __syncthreads();   // B4: h1new/sRH consumption ordered for next step
    }
}

extern "C" void kernel_launch(void* const* d_in, const int* in_sizes, int n_in,
                              void* d_out, int out_size, void* d_ws, size_t ws_size,
                              hipStream_t stream) {
    (void)in_sizes; (void)n_in; (void)out_size; (void)ws_size;
    const float* x      = (const float*)d_in[0];
    const float* w_ih   = (const float*)d_in[1];
    const float* w_hh   = (const float*)d_in[2];
    const float* b_ih   = (const float*)d_in[3];
    const float* b_hh   = (const float*)d_in[4];
    const float* gate_w = (const float*)d_in[5];
    const float* gate_b = (const float*)d_in[6];
    const float* out_w  = (const float*)d_in[7];
    const float* out_b  = (const float*)d_in[8];

    f16* wsH = (f16*)d_ws;
    f16* wih = wsH;                 // 384*64   = 24576 halves
    f16* whh = wsH + 24576;         // 384*128  = 49152
    f16* gw  = wsH + 73728;         // 256*256  = 65536
    f16* ow  = wsH + 139264;        // 128*256  = 32768

    cvt_f32_f16<<<(24576 + 255) / 256, 256, 0, stream>>>(w_ih, wih, 24576);
    cvt_f32_f16<<<(49152 + 255) / 256, 256, 0, stream>>>(w_hh, whh, 49152);
    cvt_f32_f16<<<(65536 + 255) / 256, 256, 0, stream>>>(gate_w, gw, 65536);
    cvt_f32_f16<<<(32768 + 255) / 256, 256, 0, stream>>>(out_w, ow, 32768);

    gru_fused<<<NUM_BLOCKS, 512, 0, stream>>>(x, b_ih, b_hh, gate_b, out_b,
                                              wih, whh, gw, ow, (float*)d_out);
}